// Round 11
// baseline (111.322 us; speedup 1.0000x reference)
//
#include <hip/hip_runtime.h>

#define IN_F 4096
#define OUT_F 4096
#define MTOK 1024   // 2*512 tokens
#define RANK 16
#define GROUP 128

typedef short bf16x8 __attribute__((ext_vector_type(8)));
typedef float f32x4 __attribute__((ext_vector_type(4)));

__device__ __forceinline__ unsigned short f2bf(float f) {
  unsigned int u = __float_as_uint(f);
  u += 0x7fff + ((u >> 16) & 1);   // round-to-nearest-even
  return (unsigned short)(u >> 16);
}

// ---------------- kernel 1: W_q = fake_quant(w0 + lora_b @ lora_a) -> bf16 ----------------
#define QROWS 8
__global__ __launch_bounds__(256) void quant_w(const float* __restrict__ w0,
                                               const float* __restrict__ la,
                                               const float* __restrict__ lb,
                                               const float* __restrict__ qs,
                                               unsigned short* __restrict__ wq) {
  const int bid = blockIdx.x;        // 2048 blocks: (4096/QROWS) rowgroups x 4 colblocks
  const int cb  = bid & 3;
  const int rg  = bid >> 2;
  const int i   = cb * 1024 + (threadIdx.x << 2);
  const int o0  = rg * QROWS;

  float4 areg[RANK];
  #pragma unroll
  for (int r = 0; r < RANK; ++r)
    areg[r] = *reinterpret_cast<const float4*>(&la[r * IN_F + i]);

  #pragma unroll
  for (int ro = 0; ro < QROWS; ++ro) {
    const int o = o0 + ro;
    float4 w = *reinterpret_cast<const float4*>(&w0[(size_t)o * IN_F + i]);
    const float* lbr = &lb[o * RANK];
    #pragma unroll
    for (int r = 0; r < RANK; ++r) {
      const float b = lbr[r];
      w.x = fmaf(b, areg[r].x, w.x);
      w.y = fmaf(b, areg[r].y, w.y);
      w.z = fmaf(b, areg[r].z, w.z);
      w.w = fmaf(b, areg[r].w, w.w);
    }
    const float s  = qs[o * (IN_F / GROUP) + (i >> 7)];
    const float se = s + 1e-9f;
    ushort4 ov;
    ov.x = f2bf(rintf(fminf(fmaxf(w.x / se, -8.f), 7.f)) * s);
    ov.y = f2bf(rintf(fminf(fmaxf(w.y / se, -8.f), 7.f)) * s);
    ov.z = f2bf(rintf(fminf(fmaxf(w.z / se, -8.f), 7.f)) * s);
    ov.w = f2bf(rintf(fminf(fmaxf(w.w / se, -8.f), 7.f)) * s);
    *reinterpret_cast<ushort4*>(&wq[(size_t)o * IN_F + i]) = ov;
  }
}

// ---------------- kernel 2: x f32 -> bf16 ----------------
__global__ __launch_bounds__(256) void cvt_x(const float* __restrict__ x,
                                             unsigned short* __restrict__ xb) {
  const int i = (blockIdx.x * 256 + threadIdx.x) << 2;
  float4 v = *reinterpret_cast<const float4*>(&x[i]);
  ushort4 ov;
  ov.x = f2bf(v.x); ov.y = f2bf(v.y); ov.z = f2bf(v.z); ov.w = f2bf(v.w);
  *reinterpret_cast<ushort4*>(&xb[i]) = ov;
}

// ---------------- kernel 2b: C = bias (epilogue base for atomic K-split) ----------------
__global__ __launch_bounds__(256) void init_c(const float* __restrict__ bias,
                                              float* __restrict__ C) {
  const int i = blockIdx.x * 256 + threadIdx.x;       // float4 index
  const float4 b = *reinterpret_cast<const float4*>(&bias[(i & 1023) << 2]);
  *reinterpret_cast<float4*>(&C[(size_t)i << 2]) = b;
}

// ---------------- kernel 3: C += A[M,K]*B[N,K]^T (K split across blocks) ----------------
// 256x256 tile, 512 thr = 8 waves (2M x 4N), wave tile 128x64, BK=64, KSPLIT=4.
// Grid 256 = by(4) x bx(16) x kh(4), bid = (by*16+bx)*4 + kh -> the 4 by-sharers
// of a (bx,kh) B-subpanel land on one XCD (64 apart == 0 mod 8).
// T4 schedule: raw s_barrier + counted vmcnt(8) -- next-tile global_load_lds
// stays in flight across the whole compute phase (never drained to 0 mid-loop).
// Buffer overwrite safety: lgkmcnt(0)+sched_barrier+s_barrier after compute.
// Staged volume: 256 blocks x (512 rows x 1024 K x 2B)/8... = 268MB total.
// Rows 128B, row&7 chunk-XOR on pre-swizzled global source, linear LDS dest.
#define BM 256
#define BN 256
#define BK 64
#define KSPLIT 4
#define KQ (IN_F / KSPLIT)      // 1024 per block
#define NT (KQ / BK)            // 16 K-steps
#define TBUF ((BM + BN) * BK)   // 32768 shorts = 64KB per buffer

__device__ __forceinline__ void load_lds16(const void* gsrc, void* ldst) {
  __builtin_amdgcn_global_load_lds(
      (const __attribute__((address_space(1))) unsigned int*)gsrc,
      (__attribute__((address_space(3))) unsigned int*)ldst, 16, 0, 0);
}

__global__ __launch_bounds__(512, 2) void gemm_bt(const unsigned short* __restrict__ A,
                                                  const unsigned short* __restrict__ B,
                                                  float* __restrict__ C) {
  __shared__ unsigned short lds[2 * TBUF];   // 128KB
  const int tid  = threadIdx.x;
  const int lane = tid & 63;
  const int wave = tid >> 6;     // 0..7
  const int wr   = wave >> 2;    // M-half (128 rows)
  const int wc   = wave & 3;     // N-quarter (64 cols)
  const int r16  = lane & 15;
  const int hi   = lane >> 4;

  const int bid = blockIdx.x;    // 256 blocks
  const int kh  = bid & 3;
  const int bxy = bid >> 2;
  const int bx  = bxy & 15;
  const int by  = bxy >> 4;
  const int mBase = by * BM;
  const int nBase = bx * BN;
  const int kOff  = kh * KQ;

  // stage one K-step tile: 512 rows x 8 chunks(16B) = 4096 chunks; 512 thr x 8.
  auto stage = [&](int buf, int kt) {
    const int kcol = kOff + kt * BK;
    #pragma unroll
    for (int j = 0; j < 8; ++j) {
      const int chunk = tid + j * 512;            // 0..4095
      const int row   = chunk >> 3;               // 0..511 (A: 0-255, B: 256-511)
      const int clog  = (chunk & 7) ^ (row & 7);
      const unsigned short* src = (row < BM)
          ? (A + (size_t)(mBase + row) * IN_F + kcol + clog * 8)
          : (B + (size_t)(nBase + row - BM) * IN_F + kcol + clog * 8);
      load_lds16(src, &lds[buf * TBUF + chunk * 8]);
    }
  };

  f32x4 acc[8][4];
  #pragma unroll
  for (int m = 0; m < 8; ++m)
    #pragma unroll
    for (int n = 0; n < 4; ++n)
      acc[m][n] = (f32x4){0.f, 0.f, 0.f, 0.f};

  stage(0, 0);
  stage(1, 1);
  int cur = 0;
  for (int kt = 0; kt < NT; ++kt) {
    // wait for buf[cur]'s 8 loads; leave the next tile's 8 in flight (T4)
    if (kt + 1 < NT) asm volatile("s_waitcnt vmcnt(8)" ::: "memory");
    else             asm volatile("s_waitcnt vmcnt(0)" ::: "memory");
    __builtin_amdgcn_s_barrier();               // all waves: buf[cur] complete

    const unsigned short* Ls = &lds[cur * TBUF];
    const unsigned short* La = Ls + (wr * 128 + r16) * BK;
    const unsigned short* Lb = Ls + (BM + wc * 64 + r16) * BK;
    #pragma unroll
    for (int kk = 0; kk < 2; ++kk) {
      const int cswz = (((kk << 2) + hi) ^ (r16 & 7)) << 3;  // phys chunk * 8 shorts
      bf16x8 af[8], bq[4];
      #pragma unroll
      for (int m = 0; m < 8; ++m)
        af[m] = *reinterpret_cast<const bf16x8*>(La + m * 16 * BK + cswz);
      #pragma unroll
      for (int n = 0; n < 4; ++n)
        bq[n] = *reinterpret_cast<const bf16x8*>(Lb + n * 16 * BK + cswz);
      #pragma unroll
      for (int m = 0; m < 8; ++m)
        #pragma unroll
        for (int n = 0; n < 4; ++n)
          acc[m][n] = __builtin_amdgcn_mfma_f32_16x16x32_bf16(af[m], bq[n], acc[m][n], 0, 0, 0);
    }

    asm volatile("s_waitcnt lgkmcnt(0)" ::: "memory");  // my ds_reads complete
    __builtin_amdgcn_sched_barrier(0);                  // pin (rule #18)
    __builtin_amdgcn_s_barrier();                       // all waves done reading buf[cur]
    if (kt + 2 < NT) stage(cur, kt + 2);                // overwrite with tile kt+2
    cur ^= 1;
  }

  // C/D layout: col = lane&15, row = hi*4 + j  [m89-verified]
  #pragma unroll
  for (int m = 0; m < 8; ++m) {
    const int rowg = mBase + wr * 128 + m * 16 + hi * 4;
    #pragma unroll
    for (int n = 0; n < 4; ++n) {
      const int colg = nBase + wc * 64 + n * 16 + r16;
      #pragma unroll
      for (int j = 0; j < 4; ++j)
        atomicAdd(&C[(size_t)(rowg + j) * OUT_F + colg], acc[m][n][j]);
    }
  }
}

// ---------------- fallback (only if ws too small): direct recompute ----------------
__global__ void naive_out(const float* __restrict__ x, const float* __restrict__ w0,
                          const float* __restrict__ la, const float* __restrict__ lb,
                          const float* __restrict__ qs, const float* __restrict__ bias,
                          float* __restrict__ out) {
  const int n = blockIdx.x * 256 + threadIdx.x;
  const int m = blockIdx.y;
  const float* xr = &x[(size_t)m * IN_F];
  float acc = 0.f;
  for (int kg = 0; kg < IN_F / GROUP; ++kg) {
    const float s = qs[n * (IN_F / GROUP) + kg];
    const float se = s + 1e-9f;
    for (int k0 = 0; k0 < GROUP; ++k0) {
      const int k = kg * GROUP + k0;
      float w = w0[(size_t)n * IN_F + k];
      for (int r = 0; r < RANK; ++r) w = fmaf(lb[n * RANK + r], la[r * IN_F + k], w);
      const float q = rintf(fminf(fmaxf(w / se, -8.f), 7.f));
      acc = fmaf(xr[k], q * s, acc);
    }
  }
  out[(size_t)m * OUT_F + n] = acc + bias[n];
}

extern "C" void kernel_launch(void* const* d_in, const int* in_sizes, int n_in,
                              void* d_out, int out_size, void* d_ws, size_t ws_size,
                              hipStream_t stream) {
  const float* x    = (const float*)d_in[0];
  const float* w0   = (const float*)d_in[1];
  const float* la   = (const float*)d_in[2];
  const float* lb   = (const float*)d_in[3];
  const float* qs   = (const float*)d_in[4];
  const float* bias = (const float*)d_in[5];
  float* out = (float*)d_out;

  const size_t wq_bytes = (size_t)OUT_F * IN_F * 2;
  const size_t xb_bytes = (size_t)MTOK * IN_F * 2;

  if (ws_size >= wq_bytes + xb_bytes) {
    unsigned short* wq = (unsigned short*)d_ws;
    unsigned short* xb = (unsigned short*)((char*)d_ws + wq_bytes);
    quant_w<<<(OUT_F / QROWS) * 4, 256, 0, stream>>>(w0, la, lb, qs, wq);
    cvt_x<<<(MTOK * IN_F) / 1024, 256, 0, stream>>>(x, xb);
    init_c<<<(MTOK * OUT_F) / 1024, 256, 0, stream>>>(bias, out);
    // 256 blocks = 4 by x 16 bx x 4 kh; 1 block/CU, 8 waves
    gemm_bt<<<KSPLIT * (MTOK / BM) * (OUT_F / BN), 512, 0, stream>>>(xb, wq, out);
  } else {
    dim3 grid(OUT_F / 256, MTOK);
    naive_out<<<grid, 256, 0, stream>>>(x, w0, la, lb, qs, bias, out);
  }
}

// Round 13
// 110.520 us; speedup vs baseline: 1.0073x; 1.0073x over previous
//
#include <hip/hip_runtime.h>

#define IN_F 4096
#define OUT_F 4096
#define MTOK 1024   // 2*512 tokens
#define RANK 16
#define GROUP 128

typedef short bf16x8 __attribute__((ext_vector_type(8)));
typedef float f32x4 __attribute__((ext_vector_type(4)));

__device__ __forceinline__ unsigned short f2bf(float f) {
  unsigned int u = __float_as_uint(f);
  u += 0x7fff + ((u >> 16) & 1);   // round-to-nearest-even
  return (unsigned short)(u >> 16);
}

// ---------------- kernel 1: W_q = fake_quant(w0 + lora_b @ lora_a) -> bf16 ----------------
#define QROWS 8
__global__ __launch_bounds__(256) void quant_w(const float* __restrict__ w0,
                                               const float* __restrict__ la,
                                               const float* __restrict__ lb,
                                               const float* __restrict__ qs,
                                               unsigned short* __restrict__ wq) {
  const int bid = blockIdx.x;        // 2048 blocks: (4096/QROWS) rowgroups x 4 colblocks
  const int cb  = bid & 3;
  const int rg  = bid >> 2;
  const int i   = cb * 1024 + (threadIdx.x << 2);
  const int o0  = rg * QROWS;

  float4 areg[RANK];
  #pragma unroll
  for (int r = 0; r < RANK; ++r)
    areg[r] = *reinterpret_cast<const float4*>(&la[r * IN_F + i]);

  #pragma unroll
  for (int ro = 0; ro < QROWS; ++ro) {
    const int o = o0 + ro;
    float4 w = *reinterpret_cast<const float4*>(&w0[(size_t)o * IN_F + i]);
    const float* lbr = &lb[o * RANK];
    #pragma unroll
    for (int r = 0; r < RANK; ++r) {
      const float b = lbr[r];
      w.x = fmaf(b, areg[r].x, w.x);
      w.y = fmaf(b, areg[r].y, w.y);
      w.z = fmaf(b, areg[r].z, w.z);
      w.w = fmaf(b, areg[r].w, w.w);
    }
    const float s  = qs[o * (IN_F / GROUP) + (i >> 7)];
    const float se = s + 1e-9f;
    ushort4 ov;
    ov.x = f2bf(rintf(fminf(fmaxf(w.x / se, -8.f), 7.f)) * s);
    ov.y = f2bf(rintf(fminf(fmaxf(w.y / se, -8.f), 7.f)) * s);
    ov.z = f2bf(rintf(fminf(fmaxf(w.z / se, -8.f), 7.f)) * s);
    ov.w = f2bf(rintf(fminf(fmaxf(w.w / se, -8.f), 7.f)) * s);
    *reinterpret_cast<ushort4*>(&wq[(size_t)o * IN_F + i]) = ov;
  }
}

// ---------------- kernel 2: x f32 -> bf16 ----------------
__global__ __launch_bounds__(256) void cvt_x(const float* __restrict__ x,
                                             unsigned short* __restrict__ xb) {
  const int i = (blockIdx.x * 256 + threadIdx.x) << 2;
  float4 v = *reinterpret_cast<const float4*>(&x[i]);
  ushort4 ov;
  ov.x = f2bf(v.x); ov.y = f2bf(v.y); ov.z = f2bf(v.z); ov.w = f2bf(v.w);
  *reinterpret_cast<ushort4*>(&xb[i]) = ov;
}

// ---------------- kernel 2b: C = bias (epilogue base for atomic K-split) ----------------
__global__ __launch_bounds__(256) void init_c(const float* __restrict__ bias,
                                              float* __restrict__ C) {
  const int i = blockIdx.x * 256 + threadIdx.x;       // float4 index
  const float4 b = *reinterpret_cast<const float4*>(&bias[(i & 1023) << 2]);
  *reinterpret_cast<float4*>(&C[(size_t)i << 2]) = b;
}

// ---------------- kernel 3: C += A[M,K]*B[N,K]^T (K split across blocks) ----------------
// 256x256 tile, 512 thr = 8 waves (2M x 4N), wave tile 128x64, BK=64, KSPLIT=4.
// R4-proven robust 2-buffer __syncthreads loop (sync -> stage next -> compute):
// the drain at sync only waits the tail of loads that had a full compute phase
// to progress (R4 measured 11.8 TB/s staging = ceiling).
// bid = kh*64 + by*16 + bx  ->  XCD = bid%8 = bx&7:
//   - all 4 kh-contenders of tile (by,bx) on ONE XCD -> atomics bounce L2-locally
//   - all 4 by-sharers of a B-panel on that XCD; 2 bx-panels = 4MB = its L2
// Staged volume: 256 blocks x 1MB = 268MB (the minimum at 256^2 tiles).
// Rows 128B, row&7 chunk-XOR on pre-swizzled global source, linear LDS dest.
#define BM 256
#define BN 256
#define BK 64
#define KSPLIT 4
#define KQ (IN_F / KSPLIT)      // 1024 per block
#define NT (KQ / BK)            // 16 K-steps
#define TBUF ((BM + BN) * BK)   // 32768 shorts = 64KB per buffer

__device__ __forceinline__ void load_lds16(const void* gsrc, void* ldst) {
  __builtin_amdgcn_global_load_lds(
      (const __attribute__((address_space(1))) unsigned int*)gsrc,
      (__attribute__((address_space(3))) unsigned int*)ldst, 16, 0, 0);
}

__global__ __launch_bounds__(512, 2) void gemm_bt(const unsigned short* __restrict__ A,
                                                  const unsigned short* __restrict__ B,
                                                  float* __restrict__ C) {
  __shared__ unsigned short lds[2 * TBUF];   // 128KB
  const int tid  = threadIdx.x;
  const int lane = tid & 63;
  const int wave = tid >> 6;     // 0..7
  const int wr   = wave >> 2;    // M-half (128 rows)
  const int wc   = wave & 3;     // N-quarter (64 cols)
  const int r16  = lane & 15;
  const int hi   = lane >> 4;

  const int bid = blockIdx.x;    // 256 blocks
  const int kh  = bid >> 6;      // 0..3
  const int by  = (bid >> 4) & 3;
  const int bx  = bid & 15;
  const int mBase = by * BM;
  const int nBase = bx * BN;
  const int kOff  = kh * KQ;

  // stage one K-step tile: 512 rows x 8 chunks(16B) = 4096 chunks; 512 thr x 8.
  auto stage = [&](int buf, int kt) {
    const int kcol = kOff + kt * BK;
    #pragma unroll
    for (int j = 0; j < 8; ++j) {
      const int chunk = tid + j * 512;            // 0..4095
      const int row   = chunk >> 3;               // 0..511 (A: 0-255, B: 256-511)
      const int clog  = (chunk & 7) ^ (row & 7);
      const unsigned short* src = (row < BM)
          ? (A + (size_t)(mBase + row) * IN_F + kcol + clog * 8)
          : (B + (size_t)(nBase + row - BM) * IN_F + kcol + clog * 8);
      load_lds16(src, &lds[buf * TBUF + chunk * 8]);
    }
  };

  f32x4 acc[8][4];
  #pragma unroll
  for (int m = 0; m < 8; ++m)
    #pragma unroll
    for (int n = 0; n < 4; ++n)
      acc[m][n] = (f32x4){0.f, 0.f, 0.f, 0.f};

  stage(0, 0);
  int cur = 0;
  for (int kt = 0; kt < NT; ++kt) {
    __syncthreads();                     // stage(cur) drained; buf cur^1 free
    if (kt + 1 < NT) stage(cur ^ 1, kt + 1);

    const unsigned short* Ls = &lds[cur * TBUF];
    const unsigned short* La = Ls + (wr * 128 + r16) * BK;
    const unsigned short* Lb = Ls + (BM + wc * 64 + r16) * BK;
    #pragma unroll
    for (int kk = 0; kk < 2; ++kk) {
      const int cswz = (((kk << 2) + hi) ^ (r16 & 7)) << 3;  // phys chunk * 8 shorts
      bf16x8 af[8], bq[4];
      #pragma unroll
      for (int m = 0; m < 8; ++m)
        af[m] = *reinterpret_cast<const bf16x8*>(La + m * 16 * BK + cswz);
      #pragma unroll
      for (int n = 0; n < 4; ++n)
        bq[n] = *reinterpret_cast<const bf16x8*>(Lb + n * 16 * BK + cswz);
      #pragma unroll
      for (int m = 0; m < 8; ++m)
        #pragma unroll
        for (int n = 0; n < 4; ++n)
          acc[m][n] = __builtin_amdgcn_mfma_f32_16x16x32_bf16(af[m], bq[n], acc[m][n], 0, 0, 0);
    }
    cur ^= 1;
  }

  // C/D layout: col = lane&15, row = hi*4 + j  [m89-verified]
  #pragma unroll
  for (int m = 0; m < 8; ++m) {
    const int rowg = mBase + wr * 128 + m * 16 + hi * 4;
    #pragma unroll
    for (int n = 0; n < 4; ++n) {
      const int colg = nBase + wc * 64 + n * 16 + r16;
      #pragma unroll
      for (int j = 0; j < 4; ++j)
        atomicAdd(&C[(size_t)(rowg + j) * OUT_F + colg], acc[m][n][j]);
    }
  }
}

// ---------------- fallback (only if ws too small): direct recompute ----------------
__global__ void naive_out(const float* __restrict__ x, const float* __restrict__ w0,
                          const float* __restrict__ la, const float* __restrict__ lb,
                          const float* __restrict__ qs, const float* __restrict__ bias,
                          float* __restrict__ out) {
  const int n = blockIdx.x * 256 + threadIdx.x;
  const int m = blockIdx.y;
  const float* xr = &x[(size_t)m * IN_F];
  float acc = 0.f;
  for (int kg = 0; kg < IN_F / GROUP; ++kg) {
    const float s = qs[n * (IN_F / GROUP) + kg];
    const float se = s + 1e-9f;
    for (int k0 = 0; k0 < GROUP; ++k0) {
      const int k = kg * GROUP + k0;
      float w = w0[(size_t)n * IN_F + k];
      for (int r = 0; r < RANK; ++r) w = fmaf(lb[n * RANK + r], la[r * IN_F + k], w);
      const float q = rintf(fminf(fmaxf(w / se, -8.f), 7.f));
      acc = fmaf(xr[k], q * s, acc);
    }
  }
  out[(size_t)m * OUT_F + n] = acc + bias[n];
}

extern "C" void kernel_launch(void* const* d_in, const int* in_sizes, int n_in,
                              void* d_out, int out_size, void* d_ws, size_t ws_size,
                              hipStream_t stream) {
  const float* x    = (const float*)d_in[0];
  const float* w0   = (const float*)d_in[1];
  const float* la   = (const float*)d_in[2];
  const float* lb   = (const float*)d_in[3];
  const float* qs   = (const float*)d_in[4];
  const float* bias = (const float*)d_in[5];
  float* out = (float*)d_out;

  const size_t wq_bytes = (size_t)OUT_F * IN_F * 2;
  const size_t xb_bytes = (size_t)MTOK * IN_F * 2;

  if (ws_size >= wq_bytes + xb_bytes) {
    unsigned short* wq = (unsigned short*)d_ws;
    unsigned short* xb = (unsigned short*)((char*)d_ws + wq_bytes);
    quant_w<<<(OUT_F / QROWS) * 4, 256, 0, stream>>>(w0, la, lb, qs, wq);
    cvt_x<<<(MTOK * IN_F) / 1024, 256, 0, stream>>>(x, xb);
    init_c<<<(MTOK * OUT_F) / 1024, 256, 0, stream>>>(bias, out);
    // 256 blocks = kh*64 + by*16 + bx; XCD = bx&7
    gemm_bt<<<KSPLIT * (MTOK / BM) * (OUT_F / BN), 512, 0, stream>>>(xb, wq, out);
  } else {
    dim3 grid(OUT_F / 256, MTOK);
    naive_out<<<grid, 256, 0, stream>>>(x, w0, la, lb, qs, bias, out);
  }
}

// Round 15
// 108.628 us; speedup vs baseline: 1.0248x; 1.0174x over previous
//
#include <hip/hip_runtime.h>

#define IN_F 4096
#define OUT_F 4096
#define MTOK 1024   // 2*512 tokens
#define RANK 16
#define GROUP 128

typedef short bf16x8 __attribute__((ext_vector_type(8)));
typedef float f32x4 __attribute__((ext_vector_type(4)));

__device__ __forceinline__ unsigned short f2bf(float f) {
  unsigned int u = __float_as_uint(f);
  u += 0x7fff + ((u >> 16) & 1);   // round-to-nearest-even
  return (unsigned short)(u >> 16);
}

// ---------------- kernel 1: W_q = fake_quant(w0 + lora_b @ lora_a) -> bf16 ----------------
#define QROWS 8
__global__ __launch_bounds__(256) void quant_w(const float* __restrict__ w0,
                                               const float* __restrict__ la,
                                               const float* __restrict__ lb,
                                               const float* __restrict__ qs,
                                               unsigned short* __restrict__ wq) {
  const int bid = blockIdx.x;        // 2048 blocks: (4096/QROWS) rowgroups x 4 colblocks
  const int cb  = bid & 3;
  const int rg  = bid >> 2;
  const int i   = cb * 1024 + (threadIdx.x << 2);
  const int o0  = rg * QROWS;

  float4 areg[RANK];
  #pragma unroll
  for (int r = 0; r < RANK; ++r)
    areg[r] = *reinterpret_cast<const float4*>(&la[r * IN_F + i]);

  #pragma unroll
  for (int ro = 0; ro < QROWS; ++ro) {
    const int o = o0 + ro;
    float4 w = *reinterpret_cast<const float4*>(&w0[(size_t)o * IN_F + i]);
    const float* lbr = &lb[o * RANK];
    #pragma unroll
    for (int r = 0; r < RANK; ++r) {
      const float b = lbr[r];
      w.x = fmaf(b, areg[r].x, w.x);
      w.y = fmaf(b, areg[r].y, w.y);
      w.z = fmaf(b, areg[r].z, w.z);
      w.w = fmaf(b, areg[r].w, w.w);
    }
    const float s  = qs[o * (IN_F / GROUP) + (i >> 7)];
    const float se = s + 1e-9f;
    ushort4 ov;
    ov.x = f2bf(rintf(fminf(fmaxf(w.x / se, -8.f), 7.f)) * s);
    ov.y = f2bf(rintf(fminf(fmaxf(w.y / se, -8.f), 7.f)) * s);
    ov.z = f2bf(rintf(fminf(fmaxf(w.z / se, -8.f), 7.f)) * s);
    ov.w = f2bf(rintf(fminf(fmaxf(w.w / se, -8.f), 7.f)) * s);
    *reinterpret_cast<ushort4*>(&wq[(size_t)o * IN_F + i]) = ov;
  }
}

// ---------------- kernel 2: x f32 -> bf16 ----------------
__global__ __launch_bounds__(256) void cvt_x(const float* __restrict__ x,
                                             unsigned short* __restrict__ xb) {
  const int i = (blockIdx.x * 256 + threadIdx.x) << 2;
  float4 v = *reinterpret_cast<const float4*>(&x[i]);
  ushort4 ov;
  ov.x = f2bf(v.x); ov.y = f2bf(v.y); ov.z = f2bf(v.z); ov.w = f2bf(v.w);
  *reinterpret_cast<ushort4*>(&xb[i]) = ov;
}

// ---------------- kernel 2b: C = bias (epilogue base for atomic K-split) ----------------
__global__ __launch_bounds__(256) void init_c(const float* __restrict__ bias,
                                              float* __restrict__ C) {
  const int i = blockIdx.x * 256 + threadIdx.x;       // float4 index
  const float4 b = *reinterpret_cast<const float4*>(&bias[(i & 1023) << 2]);
  *reinterpret_cast<float4*>(&C[(size_t)i << 2]) = b;
}

// ---------------- kernel 3: C += A[M,K]*B[N,K]^T (K split across blocks) ----------------
// 256x256 tile, 1024 thr = 16 waves in a 4x4 grid of 64x64 wave tiles (the
// R4-proven shape: acc[4][4]=64 regs, 8 ds_read_b128 : 16 MFMA per kk, 4
// waves/SIMD for latency hiding). BK=64, KSPLIT=4, grid 256 = kh*64+by*16+bx
// -> XCD = bx&7 (B-panels and all 4 atomic kh-contenders L2-local).
// R4 sync loop: __syncthreads -> stage(next) -> compute. LDS 128KB, 1 blk/CU.
// Staged volume = 256 blocks x 1MB = 268MB (minimum at 256^2).
// Rows 128B, row&7 chunk-XOR on pre-swizzled global source, linear LDS dest.
#define BM 256
#define BN 256
#define BK 64
#define KSPLIT 4
#define KQ (IN_F / KSPLIT)      // 1024 per block
#define NT (KQ / BK)            // 16 K-steps
#define TBUF ((BM + BN) * BK)   // 32768 shorts = 64KB per buffer

__device__ __forceinline__ void load_lds16(const void* gsrc, void* ldst) {
  __builtin_amdgcn_global_load_lds(
      (const __attribute__((address_space(1))) unsigned int*)gsrc,
      (__attribute__((address_space(3))) unsigned int*)ldst, 16, 0, 0);
}

__global__ __launch_bounds__(1024, 4) void gemm_bt(const unsigned short* __restrict__ A,
                                                   const unsigned short* __restrict__ B,
                                                   float* __restrict__ C) {
  __shared__ unsigned short lds[2 * TBUF];   // 128KB
  const int tid  = threadIdx.x;
  const int lane = tid & 63;
  const int wave = tid >> 6;     // 0..15
  const int wr   = wave >> 2;    // M-quarter (64 rows)
  const int wc   = wave & 3;     // N-quarter (64 cols)
  const int r16  = lane & 15;
  const int hi   = lane >> 4;

  const int bid = blockIdx.x;    // 256 blocks
  const int kh  = bid >> 6;      // 0..3
  const int by  = (bid >> 4) & 3;
  const int bx  = bid & 15;
  const int mBase = by * BM;
  const int nBase = bx * BN;
  const int kOff  = kh * KQ;

  // per-thread staging sources: 4096 chunks of 16B, 1024 thr -> 4 each.
  const unsigned short* src[4];
  int dstOff[4];
  #pragma unroll
  for (int j = 0; j < 4; ++j) {
    const int chunk = tid + j * 1024;           // 0..4095
    const int row   = chunk >> 3;               // 0..511 (A: 0-255, B: 256-511)
    const int clog  = (chunk & 7) ^ (row & 7);
    src[j] = ((row < BM) ? (A + (size_t)(mBase + row) * IN_F)
                         : (B + (size_t)(nBase + row - BM) * IN_F))
             + kOff + clog * 8;
    dstOff[j] = chunk * 8;
  }

  auto stage = [&](int buf, int kt) {
    #pragma unroll
    for (int j = 0; j < 4; ++j)
      load_lds16(src[j] + kt * BK, &lds[buf * TBUF + dstOff[j]]);
  };

  f32x4 acc[4][4];
  #pragma unroll
  for (int m = 0; m < 4; ++m)
    #pragma unroll
    for (int n = 0; n < 4; ++n)
      acc[m][n] = (f32x4){0.f, 0.f, 0.f, 0.f};

  stage(0, 0);
  int cur = 0;
  for (int kt = 0; kt < NT; ++kt) {
    __syncthreads();                     // stage(cur) drained; buf cur^1 free
    if (kt + 1 < NT) stage(cur ^ 1, kt + 1);

    const unsigned short* Ls = &lds[cur * TBUF];
    const unsigned short* La = Ls + (wr * 64 + r16) * BK;
    const unsigned short* Lb = Ls + (BM + wc * 64 + r16) * BK;
    #pragma unroll
    for (int kk = 0; kk < 2; ++kk) {
      const int cswz = (((kk << 2) + hi) ^ (r16 & 7)) << 3;  // phys chunk * 8 shorts
      bf16x8 af[4], bq[4];
      #pragma unroll
      for (int m = 0; m < 4; ++m)
        af[m] = *reinterpret_cast<const bf16x8*>(La + m * 16 * BK + cswz);
      #pragma unroll
      for (int n = 0; n < 4; ++n)
        bq[n] = *reinterpret_cast<const bf16x8*>(Lb + n * 16 * BK + cswz);
      #pragma unroll
      for (int m = 0; m < 4; ++m)
        #pragma unroll
        for (int n = 0; n < 4; ++n)
          acc[m][n] = __builtin_amdgcn_mfma_f32_16x16x32_bf16(af[m], bq[n], acc[m][n], 0, 0, 0);
    }
    cur ^= 1;
  }

  // C/D layout: col = lane&15, row = hi*4 + j  [m89-verified]
  #pragma unroll
  for (int m = 0; m < 4; ++m) {
    const int rowg = mBase + wr * 64 + m * 16 + hi * 4;
    #pragma unroll
    for (int n = 0; n < 4; ++n) {
      const int colg = nBase + wc * 64 + n * 16 + r16;
      #pragma unroll
      for (int j = 0; j < 4; ++j)
        atomicAdd(&C[(size_t)(rowg + j) * OUT_F + colg], acc[m][n][j]);
    }
  }
}

// ---------------- fallback (only if ws too small): direct recompute ----------------
__global__ void naive_out(const float* __restrict__ x, const float* __restrict__ w0,
                          const float* __restrict__ la, const float* __restrict__ lb,
                          const float* __restrict__ qs, const float* __restrict__ bias,
                          float* __restrict__ out) {
  const int n = blockIdx.x * 256 + threadIdx.x;
  const int m = blockIdx.y;
  const float* xr = &x[(size_t)m * IN_F];
  float acc = 0.f;
  for (int kg = 0; kg < IN_F / GROUP; ++kg) {
    const float s = qs[n * (IN_F / GROUP) + kg];
    const float se = s + 1e-9f;
    for (int k0 = 0; k0 < GROUP; ++k0) {
      const int k = kg * GROUP + k0;
      float w = w0[(size_t)n * IN_F + k];
      for (int r = 0; r < RANK; ++r) w = fmaf(lb[n * RANK + r], la[r * IN_F + k], w);
      const float q = rintf(fminf(fmaxf(w / se, -8.f), 7.f));
      acc = fmaf(xr[k], q * s, acc);
    }
  }
  out[(size_t)m * OUT_F + n] = acc + bias[n];
}

extern "C" void kernel_launch(void* const* d_in, const int* in_sizes, int n_in,
                              void* d_out, int out_size, void* d_ws, size_t ws_size,
                              hipStream_t stream) {
  const float* x    = (const float*)d_in[0];
  const float* w0   = (const float*)d_in[1];
  const float* la   = (const float*)d_in[2];
  const float* lb   = (const float*)d_in[3];
  const float* qs   = (const float*)d_in[4];
  const float* bias = (const float*)d_in[5];
  float* out = (float*)d_out;

  const size_t wq_bytes = (size_t)OUT_F * IN_F * 2;
  const size_t xb_bytes = (size_t)MTOK * IN_F * 2;

  if (ws_size >= wq_bytes + xb_bytes) {
    unsigned short* wq = (unsigned short*)d_ws;
    unsigned short* xb = (unsigned short*)((char*)d_ws + wq_bytes);
    quant_w<<<(OUT_F / QROWS) * 4, 256, 0, stream>>>(w0, la, lb, qs, wq);
    cvt_x<<<(MTOK * IN_F) / 1024, 256, 0, stream>>>(x, xb);
    init_c<<<(MTOK * OUT_F) / 1024, 256, 0, stream>>>(bias, out);
    // 256 blocks = kh*64 + by*16 + bx; XCD = bx&7; 1024 threads = 16 waves
    gemm_bt<<<KSPLIT * (MTOK / BM) * (OUT_F / BN), 1024, 0, stream>>>(xb, wq, out);
  } else {
    dim3 grid(OUT_F / 256, MTOK);
    naive_out<<<grid, 256, 0, stream>>>(x, w0, la, lb, qs, bias, out);
  }
}

// Round 19
// 63.027 us; speedup vs baseline: 1.7663x; 1.7235x over previous
//
#include <hip/hip_runtime.h>

#define IN_F 4096
#define OUT_F 4096
#define MTOK 1024   // 2*512 tokens
#define RANK 16
#define GROUP 128

typedef short bf16x8 __attribute__((ext_vector_type(8)));
typedef float f32x4 __attribute__((ext_vector_type(4)));

__device__ __forceinline__ unsigned short f2bf(float f) {
  unsigned int u = __float_as_uint(f);
  u += 0x7fff + ((u >> 16) & 1);   // round-to-nearest-even
  return (unsigned short)(u >> 16);
}

// ---------------- kernel 1: fused prep ----------------
// blocks 0..2047: W_q = fake_quant(w0 + lora_b@lora_a) -> bf16 (QROWS=8 rows x 1024 cols each)
// blocks 2048..2559: x f32 -> bf16 (4096 elems each)
#define QROWS 8
__global__ __launch_bounds__(256) void prep(const float* __restrict__ w0,
                                            const float* __restrict__ la,
                                            const float* __restrict__ lb,
                                            const float* __restrict__ qs,
                                            const float* __restrict__ x,
                                            unsigned short* __restrict__ wq,
                                            unsigned short* __restrict__ xb) {
  const int bid = blockIdx.x;
  if (bid >= 2048) {                 // ---- cvt_x part ----
    const int i = ((bid - 2048) * 256 + threadIdx.x) << 2;
    float4 v = *reinterpret_cast<const float4*>(&x[i]);
    ushort4 ov;
    ov.x = f2bf(v.x); ov.y = f2bf(v.y); ov.z = f2bf(v.z); ov.w = f2bf(v.w);
    *reinterpret_cast<ushort4*>(&xb[i]) = ov;
    return;
  }
  // ---- quant_w part ----
  const int cb  = bid & 3;
  const int rg  = bid >> 2;
  const int i   = cb * 1024 + (threadIdx.x << 2);
  const int o0  = rg * QROWS;

  float4 areg[RANK];
  #pragma unroll
  for (int r = 0; r < RANK; ++r)
    areg[r] = *reinterpret_cast<const float4*>(&la[r * IN_F + i]);

  #pragma unroll
  for (int ro = 0; ro < QROWS; ++ro) {
    const int o = o0 + ro;
    float4 w = *reinterpret_cast<const float4*>(&w0[(size_t)o * IN_F + i]);
    const float* lbr = &lb[o * RANK];
    #pragma unroll
    for (int r = 0; r < RANK; ++r) {
      const float b = lbr[r];
      w.x = fmaf(b, areg[r].x, w.x);
      w.y = fmaf(b, areg[r].y, w.y);
      w.z = fmaf(b, areg[r].z, w.z);
      w.w = fmaf(b, areg[r].w, w.w);
    }
    const float s  = qs[o * (IN_F / GROUP) + (i >> 7)];
    const float se = s + 1e-9f;
    ushort4 ov;
    ov.x = f2bf(rintf(fminf(fmaxf(w.x / se, -8.f), 7.f)) * s);
    ov.y = f2bf(rintf(fminf(fmaxf(w.y / se, -8.f), 7.f)) * s);
    ov.z = f2bf(rintf(fminf(fmaxf(w.z / se, -8.f), 7.f)) * s);
    ov.w = f2bf(rintf(fminf(fmaxf(w.w / se, -8.f), 7.f)) * s);
    *reinterpret_cast<ushort4*>(&wq[(size_t)o * IN_F + i]) = ov;
  }
}

// ---------------- kernel 2: C[M,N] = A[M,K]*B[N,K]^T + bias (R4-proven) ----------------
// 512 threads = 2 K-groups x 4 waves. Block tile 128x128; each group does K=2048.
// Wave tile 64x64 (4x4 frags of 16x16x32): 16 MFMA per 8 ds_read_b128.
// LDS: per group 2 buffers x (A[128][64] + B[128][64]) shorts = 64KB; total 128KB.
// Chunk swizzle: phys16Bchunk = logchunk ^ (row&7) (applied on global src; LDS linear).
// Measured (R4): gemm 45.6 us, 536 MB staged = 11.8 TB/s (empirical staging ceiling),
// 0 bank conflicts. Direct C write with bias (no atomics, no init pass).
#define BM 128
#define BN 128
#define BK 64
#define KSPLIT 2
#define KHALF (IN_F / KSPLIT)   // 2048
#define NT (KHALF / BK)         // 32
#define GBUF 16384              // shorts per buffer per group

__device__ __forceinline__ void load_lds16(const void* gsrc, void* ldst) {
  __builtin_amdgcn_global_load_lds(
      (const __attribute__((address_space(1))) unsigned int*)gsrc,
      (__attribute__((address_space(3))) unsigned int*)ldst, 16, 0, 0);
}

__global__ __launch_bounds__(512, 2) void gemm_bt(const unsigned short* __restrict__ A,
                                                  const unsigned short* __restrict__ B,
                                                  const float* __restrict__ bias,
                                                  float* __restrict__ C) {
  __shared__ unsigned short lds[2 * 2 * GBUF];   // [group][buf][16384] = 128KB
  const int tid  = threadIdx.x;
  const int wave = tid >> 6;
  const int lane = tid & 63;
  const int grp  = wave >> 2;
  const int wg   = wave & 3;
  const int wr   = wg >> 1, wc = wg & 1;         // 2x2 waves over 128x128, wave tile 64x64
  const int mBase = blockIdx.y * BM;
  const int nBase = blockIdx.x * BN;
  const int r16 = lane & 15;
  const int hi  = lane >> 4;

  unsigned short* gl = &lds[grp * 2 * GBUF];
  const size_t kOff = (size_t)grp * KHALF;

  auto stage = [&](int buf, int kt) {
    const size_t kcol = kOff + kt * BK;
    #pragma unroll
    for (int j = 0; j < 8; ++j) {
      const int chunk = (tid & 255) + j * 256;      // 0..2047 (16B units)
      const int row   = chunk >> 3;                 // 8 chunks per 64-short row
      const int clog  = (chunk & 7) ^ (row & 7);
      const unsigned short* src = (row < BM)
          ? (A + (size_t)(mBase + row) * IN_F + kcol + clog * 8)
          : (B + (size_t)(nBase + row - BM) * IN_F + kcol + clog * 8);
      load_lds16(src, &gl[buf * GBUF + chunk * 8]);
    }
  };

  f32x4 acc[4][4];
  #pragma unroll
  for (int m = 0; m < 4; ++m)
    #pragma unroll
    for (int n = 0; n < 4; ++n)
      acc[m][n] = (f32x4){0.f, 0.f, 0.f, 0.f};

  stage(0, 0);
  int cur = 0;
  for (int kt = 0; kt < NT; ++kt) {
    __syncthreads();                       // stage(cur) drained; cur^1 free
    if (kt + 1 < NT) stage(cur ^ 1, kt + 1);
    const unsigned short* Ls = &gl[cur * GBUF];
    const unsigned short* La = Ls + (wr * 64 + r16) * BK;
    const unsigned short* Lb = Ls + (BM + wc * 64 + r16) * BK;
    #pragma unroll
    for (int kk = 0; kk < 2; ++kk) {
      const int cswz = (((kk << 2) + hi) ^ (r16 & 7)) << 3;
      bf16x8 af[4], bq[4];
      #pragma unroll
      for (int m = 0; m < 4; ++m)
        af[m] = *reinterpret_cast<const bf16x8*>(La + m * 16 * BK + cswz);
      #pragma unroll
      for (int n = 0; n < 4; ++n)
        bq[n] = *reinterpret_cast<const bf16x8*>(Lb + n * 16 * BK + cswz);
      #pragma unroll
      for (int m = 0; m < 4; ++m)
        #pragma unroll
        for (int n = 0; n < 4; ++n)
          acc[m][n] = __builtin_amdgcn_mfma_f32_16x16x32_bf16(af[m], bq[n], acc[m][n], 0, 0, 0);
    }
    cur ^= 1;
  }

  // ---- cross-group reduce through LDS (reuse staging space; all reads done) ----
  __syncthreads();
  float* ex = reinterpret_cast<float*>(&lds[2 * GBUF]);   // group-1 region, 16384 floats
  if (grp == 1) {
    #pragma unroll
    for (int m = 0; m < 4; ++m)
      #pragma unroll
      for (int n = 0; n < 4; ++n)
        *reinterpret_cast<f32x4*>(&ex[wg * 4096 + (m * 4 + n) * 256 + lane * 4]) = acc[m][n];
  }
  __syncthreads();
  if (grp == 0) {
    #pragma unroll
    for (int m = 0; m < 4; ++m) {
      const int rowg = mBase + wr * 64 + m * 16 + hi * 4;
      #pragma unroll
      for (int n = 0; n < 4; ++n) {
        const f32x4 p = *reinterpret_cast<const f32x4*>(&ex[wg * 4096 + (m * 4 + n) * 256 + lane * 4]);
        const int colg = nBase + wc * 64 + n * 16 + r16;
        const float bv = bias[colg];
        #pragma unroll
        for (int j = 0; j < 4; ++j)
          C[(size_t)(rowg + j) * OUT_F + colg] = acc[m][n][j] + p[j] + bv;
      }
    }
  }
}

// ---------------- fallback (only if ws too small): direct recompute ----------------
__global__ void naive_out(const float* __restrict__ x, const float* __restrict__ w0,
                          const float* __restrict__ la, const float* __restrict__ lb,
                          const float* __restrict__ qs, const float* __restrict__ bias,
                          float* __restrict__ out) {
  const int n = blockIdx.x * 256 + threadIdx.x;
  const int m = blockIdx.y;
  const float* xr = &x[(size_t)m * IN_F];
  float acc = 0.f;
  for (int kg = 0; kg < IN_F / GROUP; ++kg) {
    const float s = qs[n * (IN_F / GROUP) + kg];
    const float se = s + 1e-9f;
    for (int k0 = 0; k0 < GROUP; ++k0) {
      const int k = kg * GROUP + k0;
      float w = w0[(size_t)n * IN_F + k];
      for (int r = 0; r < RANK; ++r) w = fmaf(lb[n * RANK + r], la[r * IN_F + k], w);
      const float q = rintf(fminf(fmaxf(w / se, -8.f), 7.f));
      acc = fmaf(xr[k], q * s, acc);
    }
  }
  out[(size_t)m * OUT_F + n] = acc + bias[n];
}

extern "C" void kernel_launch(void* const* d_in, const int* in_sizes, int n_in,
                              void* d_out, int out_size, void* d_ws, size_t ws_size,
                              hipStream_t stream) {
  const float* x    = (const float*)d_in[0];
  const float* w0   = (const float*)d_in[1];
  const float* la   = (const float*)d_in[2];
  const float* lb   = (const float*)d_in[3];
  const float* qs   = (const float*)d_in[4];
  const float* bias = (const float*)d_in[5];
  float* out = (float*)d_out;

  const size_t wq_bytes = (size_t)OUT_F * IN_F * 2;
  const size_t xb_bytes = (size_t)MTOK * IN_F * 2;

  if (ws_size >= wq_bytes + xb_bytes) {
    unsigned short* wq = (unsigned short*)d_ws;
    unsigned short* xb = (unsigned short*)((char*)d_ws + wq_bytes);
    // fused prologue: 2048 quant blocks + 512 cvt blocks in one dispatch
    prep<<<2048 + (MTOK * IN_F) / 1024, 256, 0, stream>>>(w0, la, lb, qs, x, wq, xb);
    dim3 grid(OUT_F / BN, MTOK / BM);   // 32 x 8 = 256 blocks
    gemm_bt<<<grid, 512, 0, stream>>>(xb, wq, bias, out);
  } else {
    dim3 grid(OUT_F / 256, MTOK);
    naive_out<<<grid, 256, 0, stream>>>(x, w0, la, lb, qs, bias, out);
  }
}